// Round 1
// baseline (169.464 us; speedup 1.0000x reference)
//
#include <hip/hip_runtime.h>
#include <math.h>

#define B_ROWS 16384
#define K_CB   512
#define D_DIM  256
#define NSEG   511      // K_CB - 1 segments
#define BM     64       // rows per block (main kernel)
#define NGROUPS 5       // ceil(511 / 126)
#define SEGS_PER_GROUP 126

// ---------- kernel 0: per-segment constants ----------
// sls[j] = ||c_{j+1}-c_j||^2 + 1e-8 ; cs[j] = c_j . (c_{j+1}-c_j) ; cc[j] = ||c_j||^2
__global__ __launch_bounds__(64) void seg_consts_kernel(const float* __restrict__ cb,
                                                        float* __restrict__ sls,
                                                        float* __restrict__ cs,
                                                        float* __restrict__ cc) {
    int j = blockIdx.x;            // 0..510
    int lane = threadIdx.x;        // 0..63 ; one float4 per lane (64*4 = 256 dims)
    const float4* a4 = reinterpret_cast<const float4*>(cb + (size_t)j * D_DIM);
    const float4* b4 = reinterpret_cast<const float4*>(cb + (size_t)(j + 1) * D_DIM);
    float4 a = a4[lane];
    float4 b = b4[lane];
    float sx = b.x - a.x, sy = b.y - a.y, sz = b.z - a.z, sw = b.w - a.w;
    float p_sls = sx*sx + sy*sy + sz*sz + sw*sw;
    float p_cs  = a.x*sx + a.y*sy + a.z*sz + a.w*sw;
    float p_cc  = a.x*a.x + a.y*a.y + a.z*a.z + a.w*a.w;
    #pragma unroll
    for (int m = 32; m >= 1; m >>= 1) {
        p_sls += __shfl_xor(p_sls, m, 64);
        p_cs  += __shfl_xor(p_cs,  m, 64);
        p_cc  += __shfl_xor(p_cc,  m, 64);
    }
    if (lane == 0) {
        sls[j] = p_sls + 1e-8f;
        cs[j]  = p_cs;
        cc[j]  = p_cc;
    }
}

// ---------- kernel 1: fused GEMM (W = z.C^T tile) + segment scan ----------
// grid = (B/BM, NGROUPS). Each block: 64 rows x one 126-segment group,
// processed as 2 chunks of 64 columns (63 segments each, 1-col overlap).
__global__ __launch_bounds__(256) void main_kernel(const float* __restrict__ z,
                                                   const float* __restrict__ cb,
                                                   const float* __restrict__ sls_g,
                                                   const float* __restrict__ cs_g,
                                                   const float* __restrict__ cc_g,
                                                   float4* __restrict__ cand) {
    __shared__ __align__(16) float zs[64][68];   // 68-float stride: 16B-aligned rows, conflict-light
    __shared__ __align__(16) float csh[64][68];
    __shared__ float W[64][65];
    __shared__ float zzs[64];
    __shared__ float bd2s[64];
    __shared__ float bts[64];
    __shared__ int   bidxs[64];

    int t = threadIdx.x;
    int row0 = blockIdx.x * BM;
    int seg_base = blockIdx.y * SEGS_PER_GROUP;
    int tr = t >> 4;     // 0..15 -> rows tr + 16*r
    int tc = t & 15;     // 0..15 -> cols tc + 16*c

    // per-row ||z||^2 (4 lanes per row)
    {
        int r = t >> 2, q = t & 3;
        const float4* zp = reinterpret_cast<const float4*>(z + (size_t)(row0 + r) * D_DIM + q * 64);
        float s = 0.f;
        #pragma unroll
        for (int i = 0; i < 16; ++i) {
            float4 v = zp[i];
            s += v.x*v.x + v.y*v.y + v.z*v.z + v.w*v.w;
        }
        s += __shfl_xor(s, 1, 64);
        s += __shfl_xor(s, 2, 64);
        if (q == 0) zzs[r] = s;
    }
    if (t < 64) { bd2s[t] = INFINITY; bidxs[t] = 0x7fffffff; bts[t] = 0.f; }
    __syncthreads();

    for (int ch = 0; ch < 2; ++ch) {
        int col0 = seg_base + ch * 63;
        if (col0 > NSEG - 1) break;     // uniform: only group 4 / ch 1

        float acc[4][4];
        #pragma unroll
        for (int r = 0; r < 4; ++r)
            #pragma unroll
            for (int c = 0; c < 4; ++c) acc[r][c] = 0.f;

        for (int dk = 0; dk < 4; ++dk) {
            int d0 = dk * 64;
            // stage 64x64 z tile and 64x64 codebook tile (coalesced float4)
            #pragma unroll
            for (int i = 0; i < 4; ++i) {
                int f  = i * 256 + t;
                int r  = f >> 4;         // tile row 0..63
                int dq = f & 15;         // float4 slot in row
                float4 v = *reinterpret_cast<const float4*>(z + (size_t)(row0 + r) * D_DIM + d0 + dq * 4);
                *reinterpret_cast<float4*>(&zs[r][dq * 4]) = v;
                int gc = col0 + r;
                float4 w;
                if (gc < K_CB) w = *reinterpret_cast<const float4*>(cb + (size_t)gc * D_DIM + d0 + dq * 4);
                else           w = make_float4(0.f, 0.f, 0.f, 0.f);
                *reinterpret_cast<float4*>(&csh[r][dq * 4]) = w;
            }
            __syncthreads();
            #pragma unroll
            for (int d4 = 0; d4 < 16; ++d4) {
                float4 za[4], cv[4];
                #pragma unroll
                for (int r = 0; r < 4; ++r) za[r] = *reinterpret_cast<const float4*>(&zs[tr + 16 * r][d4 * 4]);
                #pragma unroll
                for (int c = 0; c < 4; ++c) cv[c] = *reinterpret_cast<const float4*>(&csh[tc + 16 * c][d4 * 4]);
                #pragma unroll
                for (int r = 0; r < 4; ++r)
                    #pragma unroll
                    for (int c = 0; c < 4; ++c) {
                        acc[r][c] += za[r].x * cv[c].x;
                        acc[r][c] += za[r].y * cv[c].y;
                        acc[r][c] += za[r].z * cv[c].z;
                        acc[r][c] += za[r].w * cv[c].w;
                    }
            }
            __syncthreads();
        }

        // W tile to LDS
        #pragma unroll
        for (int r = 0; r < 4; ++r)
            #pragma unroll
            for (int c = 0; c < 4; ++c)
                W[tr + 16 * r][tc + 16 * c] = acc[r][c];
        __syncthreads();

        // scan segments col0 .. min(col0+62, 510)
        int seg_hi = min(col0 + 62, NSEG - 1);
        #pragma unroll
        for (int r = 0; r < 4; ++r) {
            int row = tr + 16 * r;
            float zzr = zzs[row];
            float bd = INFINITY; int bj = 0x7fffffff; float btt = 0.f;
            #pragma unroll
            for (int c = 0; c < 4; ++c) {
                int jl = tc + 16 * c;
                int j  = col0 + jl;
                if (jl < 63 && j <= seg_hi) {
                    float w0 = W[row][jl];
                    float w1 = W[row][jl + 1];
                    float slsj = sls_g[j], csj = cs_g[j], ccj = cc_g[j];
                    float dot = w1 - w0 - csj;
                    float tt = dot / slsj;
                    tt = fminf(fmaxf(tt, 0.f), 1.f);
                    float d2 = zzr - 2.f * w0 + ccj - 2.f * tt * dot + tt * tt * slsj;
                    d2 = fmaxf(d2, 0.f);
                    if (d2 < bd) { bd = d2; bj = j; btt = tt; }   // ascending j within thread -> first-min
                }
            }
            // 16-lane group argmin (first index on ties)
            #pragma unroll
            for (int m = 8; m >= 1; m >>= 1) {
                float od = __shfl_xor(bd, m, 64);
                int   oj = __shfl_xor(bj, m, 64);
                float ot = __shfl_xor(btt, m, 64);
                if (od < bd || (od == bd && oj < bj)) { bd = od; bj = oj; btt = ot; }
            }
            if (tc == 0) {
                if (bd < bd2s[row] || (bd == bd2s[row] && bj < bidxs[row])) {
                    bd2s[row] = bd; bidxs[row] = bj; bts[row] = btt;
                }
            }
        }
        __syncthreads();
    }

    if (t < 64) {
        cand[(size_t)blockIdx.y * B_ROWS + row0 + t] =
            make_float4(bd2s[t], bts[t], (float)bidxs[t], 0.f);
    }
}

// ---------- kernel 2: combine candidates + write outputs ----------
__global__ __launch_bounds__(256) void combine_kernel(const float4* __restrict__ cand,
                                                      const float* __restrict__ cb,
                                                      float* __restrict__ out) {
    float* out_bp  = out;
    float* out_idx = out + (size_t)B_ROWS * D_DIM;
    float* out_t   = out_idx + B_ROWS;
    float* out_d   = out_t + B_ROWS;

    __shared__ float4 sel[4];
    int t = threadIdx.x;
    int rloc = t >> 6, lane = t & 63;
    int row = blockIdx.x * 4 + rloc;

    if (lane == 0) {
        float bd = INFINITY; float bt = 0.f; int bj = 0x7fffffff;
        #pragma unroll
        for (int g = 0; g < NGROUPS; ++g) {
            float4 cg = cand[(size_t)g * B_ROWS + row];
            int j = (int)cg.z;
            if (cg.x < bd || (cg.x == bd && j < bj)) { bd = cg.x; bt = cg.y; bj = j; }
        }
        sel[rloc] = make_float4(bd, bt, (float)bj, 0.f);
    }
    __syncthreads();

    float4 s = sel[rloc];
    int j = (int)s.z;
    float tt = s.y;
    const float4* c0 = reinterpret_cast<const float4*>(cb + (size_t)j * D_DIM);
    const float4* c1 = reinterpret_cast<const float4*>(cb + (size_t)(j + 1) * D_DIM);
    float4 a = c0[lane], b = c1[lane];
    float4 bp = make_float4(a.x + tt * (b.x - a.x),
                            a.y + tt * (b.y - a.y),
                            a.z + tt * (b.z - a.z),
                            a.w + tt * (b.w - a.w));
    reinterpret_cast<float4*>(out_bp + (size_t)row * D_DIM)[lane] = bp;
    if (lane == 0) {
        out_idx[row] = s.z;
        out_t[row]   = tt;
        out_d[row]   = sqrtf(s.x);
    }
}

extern "C" void kernel_launch(void* const* d_in, const int* in_sizes, int n_in,
                              void* d_out, int out_size, void* d_ws, size_t ws_size,
                              hipStream_t stream) {
    const float* z  = (const float*)d_in[0];
    const float* cb = (const float*)d_in[1];
    float* ws  = (float*)d_ws;
    float* sls = ws;             // 511 floats (slot 512)
    float* cs  = ws + 512;
    float* cc  = ws + 1024;
    float4* cand = (float4*)(ws + 1536);   // byte offset 6144 (16B aligned); 5*16384 float4 = 1.25 MB
    float* out = (float*)d_out;

    seg_consts_kernel<<<NSEG, 64, 0, stream>>>(cb, sls, cs, cc);
    main_kernel<<<dim3(B_ROWS / BM, NGROUPS), 256, 0, stream>>>(z, cb, sls, cs, cc, cand);
    combine_kernel<<<B_ROWS / 4, 256, 0, stream>>>(cand, cb, out);
}

// Round 7
// 163.538 us; speedup vs baseline: 1.0362x; 1.0362x over previous
//
#include <hip/hip_runtime.h>
#include <math.h>

#define B_ROWS 16384
#define K_CB   512
#define D_DIM  256
#define NSEG   511
#define NG     4            // 4 column groups of 128 cols each

// ws float layout:
//   sls  @ 0      (512)
//   cs   @ 512    (512)
//   cc   @ 1024   (512)
//   wbnd @ 1536   (3 * 16384)   boundary cols 128,256,384 dotted with all z rows
//   zz   @ 50688  (16384)       per-row ||z||^2
//   cand @ 67072  (float4 x 16384 x 4)
#define WS_WBND 1536
#define WS_ZZ   50688
#define WS_CAND 67072

// ---------- kernel 0: segment constants + boundary dots + zz ----------
__global__ __launch_bounds__(256) void prologue_kernel(const float* __restrict__ z,
                                                       const float* __restrict__ cb,
                                                       float* __restrict__ sls,
                                                       float* __restrict__ cs,
                                                       float* __restrict__ cc,
                                                       float* __restrict__ wbnd,
                                                       float* __restrict__ zz) {
    int bid = blockIdx.x;
    int t = threadIdx.x;
    int lane = t & 63;
    if (bid < 128) {
        // segment constants: 4 segments per block, one wave each
        int j = bid * 4 + (t >> 6);
        if (j == NSEG) {            // pad slot 511 with benign values
            if (lane == 0) { sls[NSEG] = 1e30f; cs[NSEG] = 0.f; cc[NSEG] = 0.f; }
            return;
        }
        float4 a = reinterpret_cast<const float4*>(cb + (size_t)j * D_DIM)[lane];
        float4 b = reinterpret_cast<const float4*>(cb + (size_t)(j + 1) * D_DIM)[lane];
        float sx = b.x - a.x, sy = b.y - a.y, sz = b.z - a.z, sw = b.w - a.w;
        float p0 = sx*sx + sy*sy + sz*sz + sw*sw;
        float p1 = a.x*sx + a.y*sy + a.z*sz + a.w*sw;
        float p2 = a.x*a.x + a.y*a.y + a.z*a.z + a.w*a.w;
        #pragma unroll
        for (int m = 32; m >= 1; m >>= 1) {
            p0 += __shfl_xor(p0, m);
            p1 += __shfl_xor(p1, m);
            p2 += __shfl_xor(p2, m);
        }
        if (lane == 0) { sls[j] = p0 + 1e-8f; cs[j] = p1; cc[j] = p2; }
    } else {
        // boundary dots + zz: 4 rows per block, one wave each
        int row = (bid - 128) * 4 + (t >> 6);
        float4 zv = reinterpret_cast<const float4*>(z + (size_t)row * D_DIM)[lane];
        float pz = zv.x*zv.x + zv.y*zv.y + zv.z*zv.z + zv.w*zv.w;
        #pragma unroll
        for (int m = 32; m >= 1; m >>= 1) pz += __shfl_xor(pz, m);
        if (lane == 0) zz[row] = pz;
        #pragma unroll
        for (int gi = 0; gi < 3; ++gi) {
            int col = 128 * (gi + 1);
            float4 cv = reinterpret_cast<const float4*>(cb + (size_t)col * D_DIM)[lane];
            float p = zv.x*cv.x + zv.y*cv.y + zv.z*cv.z + zv.w*cv.w;
            #pragma unroll
            for (int m = 32; m >= 1; m >>= 1) p += __shfl_xor(p, m);
            if (lane == 0) wbnd[(size_t)gi * B_ROWS + row] = p;
        }
    }
}

// ---------- kernel 1: 128x128 GEMM tile + in-register segment scan ----------
__global__ __launch_bounds__(256, 2) void main_kernel(const float* __restrict__ z,
                                                      const float* __restrict__ cb,
                                                      const float* __restrict__ sls_g,
                                                      const float* __restrict__ cs_g,
                                                      const float* __restrict__ cc_g,
                                                      const float* __restrict__ wbnd,
                                                      float4* __restrict__ cand) {
    __shared__ __align__(16) float zs[128][36];   // stride 36: 144B rows (16B-mult), banks ok
    __shared__ __align__(16) float csh[128][36];
    __shared__ float sl_s[128], cs_s[128], cc_s[128];

    int t = threadIdx.x;
    int row0 = blockIdx.x * 128;
    int g = blockIdx.y;
    int col0 = g * 128;
    int tr = t >> 4;          // 0..15 -> rows tr + 16*r
    int tc = t & 15;          // 0..15 -> cols tc + 16*c
    int l = t & 63;

    if (t < 128) {
        sl_s[t] = sls_g[col0 + t];
        cs_s[t] = cs_g[col0 + t];
        cc_s[t] = cc_g[col0 + t];
    }

    float acc[8][8];
    #pragma unroll
    for (int r = 0; r < 8; ++r)
        #pragma unroll
        for (int c = 0; c < 8; ++c) acc[r][c] = 0.f;

    for (int kc = 0; kc < 8; ++kc) {
        int d0 = kc * 32;
        __syncthreads();
        // stage 128x32 z tile and 128x32 codebook tile
        #pragma unroll
        for (int i = 0; i < 4; ++i) {
            int f = i * 256 + t;          // 0..1023
            int r = f >> 3;               // 0..127
            int kq = f & 7;               // float4 slot
            float4 v = *reinterpret_cast<const float4*>(z + (size_t)(row0 + r) * D_DIM + d0 + kq * 4);
            *reinterpret_cast<float4*>(&zs[r][kq * 4]) = v;
            float4 w = *reinterpret_cast<const float4*>(cb + (size_t)(col0 + r) * D_DIM + d0 + kq * 4);
            *reinterpret_cast<float4*>(&csh[r][kq * 4]) = w;
        }
        __syncthreads();
        #pragma unroll
        for (int k4 = 0; k4 < 8; ++k4) {
            float4 za[8];
            #pragma unroll
            for (int r = 0; r < 8; ++r)
                za[r] = *reinterpret_cast<const float4*>(&zs[tr + 16 * r][k4 * 4]);
            #pragma unroll
            for (int c = 0; c < 8; ++c) {
                float4 cv = *reinterpret_cast<const float4*>(&csh[tc + 16 * c][k4 * 4]);
                #pragma unroll
                for (int r = 0; r < 8; ++r) {
                    acc[r][c] += za[r].x * cv.x;
                    acc[r][c] += za[r].y * cv.y;
                    acc[r][c] += za[r].z * cv.z;
                    acc[r][c] += za[r].w * cv.w;
                }
            }
        }
    }

    // boundary column w (col0+128) for the last segment of groups 0..2
    float wbv[8];
    #pragma unroll
    for (int r = 0; r < 8; ++r) wbv[r] = 0.f;
    if (g < 3 && tc == 15) {
        #pragma unroll
        for (int r = 0; r < 8; ++r)
            wbv[r] = wbnd[(size_t)g * B_ROWS + row0 + tr + 16 * r];
    }

    // in-register scan: segment j = col0 + tc + 16*c needs w_j (own) and w_{j+1}.
    // w_{j+1} for tc<15  : lane l+1, same chunk c           (shA)
    // w_{j+1} for tc==15 : lane tc=0 (l&48), chunk c+1      (firstw[c+1])
    //                      or wbnd for the last chunk (c==7)
    #pragma unroll
    for (int r = 0; r < 8; ++r) {
        int row = tr + 16 * r;
        // broadcast each chunk's first-column (tc=0) value to all 16 lanes
        float firstw[8];
        #pragma unroll
        for (int c = 1; c < 8; ++c) firstw[c] = __shfl(acc[r][c], l & 48);
        float bd = 1e38f; int bj = 0x3fffffff; float bt = 0.f;
        #pragma unroll
        for (int c = 0; c < 8; ++c) {
            float w0 = acc[r][c];
            float shA = __shfl(w0, l + 1);                 // lane tc+1's w (same c)
            float w1 = (tc == 15) ? ((c < 7) ? firstw[c + 1] : wbv[r]) : shA;
            int jl = tc + 16 * c;
            int j = col0 + jl;
            float slsj = sl_s[jl], csj = cs_s[jl], ccj = cc_s[jl];
            float dot = w1 - w0 - csj;
            float tt = fminf(fmaxf(dot / slsj, 0.f), 1.f);
            // relative distance (true d2 minus row-constant zz): rank-preserving
            float d2 = ccj - 2.f * w0 + tt * (tt * slsj - 2.f * dot);
            if (j < NSEG && d2 < bd) { bd = d2; bj = j; bt = tt; }
        }
        // argmin across the 16-lane column group (first index on ties)
        #pragma unroll
        for (int m = 1; m <= 8; m <<= 1) {
            float od = __shfl_xor(bd, m);
            int   oj = __shfl_xor(bj, m);
            float ot = __shfl_xor(bt, m);
            if (od < bd || (od == bd && oj < bj)) { bd = od; bj = oj; bt = ot; }
        }
        if (tc == 0)
            cand[(size_t)(row0 + row) * NG + g] = make_float4(bd, bt, (float)bj, 0.f);
    }
}

// ---------- kernel 2: combine groups + write outputs ----------
__global__ __launch_bounds__(256) void combine_kernel(const float4* __restrict__ cand,
                                                      const float* __restrict__ cb,
                                                      const float* __restrict__ zz,
                                                      float* __restrict__ out) {
    float* out_bp  = out;
    float* out_idx = out + (size_t)B_ROWS * D_DIM;
    float* out_t   = out_idx + B_ROWS;
    float* out_d   = out_t + B_ROWS;

    __shared__ float sj[256];
    __shared__ float st[256];

    int t = threadIdx.x;
    int row = blockIdx.x * 256 + t;
    const float4* cp = cand + (size_t)row * NG;
    float4 c0 = cp[0], c1 = cp[1], c2 = cp[2], c3 = cp[3];
    float bd = c0.x, bt = c0.y, bj = c0.z;
    if (c1.x < bd) { bd = c1.x; bt = c1.y; bj = c1.z; }   // groups in ascending j:
    if (c2.x < bd) { bd = c2.x; bt = c2.y; bj = c2.z; }   // strict < == first-index ties
    if (c3.x < bd) { bd = c3.x; bt = c3.y; bj = c3.z; }
    sj[t] = bj; st[t] = bt;
    out_idx[row] = bj;
    out_t[row]   = bt;
    out_d[row]   = sqrtf(fmaxf(bd + zz[row], 0.f));
    __syncthreads();

    int lane = t & 63, sub = t >> 6;
    #pragma unroll 4
    for (int it = 0; it < 64; ++it) {
        int rl = it * 4 + sub;
        int j = (int)sj[rl];
        float tt = st[rl];
        float4 a = reinterpret_cast<const float4*>(cb + (size_t)j * D_DIM)[lane];
        float4 b = reinterpret_cast<const float4*>(cb + (size_t)(j + 1) * D_DIM)[lane];
        float4 bp = make_float4(a.x + tt * (b.x - a.x),
                                a.y + tt * (b.y - a.y),
                                a.z + tt * (b.z - a.z),
                                a.w + tt * (b.w - a.w));
        reinterpret_cast<float4*>(out_bp + (size_t)(blockIdx.x * 256 + rl) * D_DIM)[lane] = bp;
    }
}

extern "C" void kernel_launch(void* const* d_in, const int* in_sizes, int n_in,
                              void* d_out, int out_size, void* d_ws, size_t ws_size,
                              hipStream_t stream) {
    const float* z  = (const float*)d_in[0];
    const float* cb = (const float*)d_in[1];
    float* ws  = (float*)d_ws;
    float* sls  = ws;
    float* cs   = ws + 512;
    float* cc   = ws + 1024;
    float* wbnd = ws + WS_WBND;
    float* zz   = ws + WS_ZZ;
    float4* cand = (float4*)(ws + WS_CAND);
    float* out = (float*)d_out;

    prologue_kernel<<<128 + B_ROWS / 4, 256, 0, stream>>>(z, cb, sls, cs, cc, wbnd, zz);
    main_kernel<<<dim3(B_ROWS / 128, NG), 256, 0, stream>>>(z, cb, sls, cs, cc, wbnd, cand);
    combine_kernel<<<B_ROWS / 256, 256, 0, stream>>>(cand, cb, zz, out);
}